// Round 1
// baseline (49.151 us; speedup 1.0000x reference)
//
#include <hip/hip_runtime.h>
#include <stdint.h>

// CachedCompressedLinear: out[b][o] = sum_k x[b][k] * ((wq[o][k]-128)*scale) + bias[o]
// x: [16][4096] f32, wq: [11008][4096] int32 codes in [0,255], scale: [1] f32, bias: [11008] f32
// out: [16][11008] f32.
// Memory-bound on the 180 MB wq stream; fuse dequant into an MFMA GEMM.

constexpr int IN_F  = 4096;
constexpr int OUT_F = 11008;
constexpr int NWAVES = 8;                         // waves per block
constexpr int KB_PER_WAVE = IN_F / 32 / NWAVES;   // 16 k-blocks of 32 per wave

typedef _Float16 f16x8 __attribute__((ext_vector_type(8)));
typedef float    f32x4 __attribute__((ext_vector_type(4)));

__global__ __launch_bounds__(NWAVES * 64, 1)
void qlinear_mfma(const float* __restrict__ x,
                  const int*   __restrict__ wq,
                  const float* __restrict__ scale,
                  const float* __restrict__ bias,
                  float*       __restrict__ out)
{
    const int tid  = threadIdx.x;
    const int lane = tid & 63;
    const int wave = tid >> 6;
    const int obase = blockIdx.x * 16;

    const int ncol = lane & 15;   // B-frag col (o_local); also A-frag row (batch b)
    const int kgrp = lane >> 4;   // 0..3

    const int o  = obase + ncol;
    const int k0 = wave * (KB_PER_WAVE * 32) + kgrp * 8;

    const float* xp = x  + (size_t)ncol * IN_F + k0;
    const int*   wp = wq + (size_t)o    * IN_F + k0;

    f32x4 acc = {0.f, 0.f, 0.f, 0.f};

    #pragma unroll 4
    for (int it = 0; it < KB_PER_WAVE; ++it) {
        const float4 xa = *reinterpret_cast<const float4*>(xp);
        const float4 xb = *reinterpret_cast<const float4*>(xp + 4);
        const int4   wa = *reinterpret_cast<const int4*>(wp);
        const int4   wb = *reinterpret_cast<const int4*>(wp + 4);

        f16x8 af, bf;
        af[0] = (_Float16)xa.x; af[1] = (_Float16)xa.y;
        af[2] = (_Float16)xa.z; af[3] = (_Float16)xa.w;
        af[4] = (_Float16)xb.x; af[5] = (_Float16)xb.y;
        af[6] = (_Float16)xb.z; af[7] = (_Float16)xb.w;

        // codes are ints in [0,255]; (c-128) in [-128,127] is EXACT in f16
        bf[0] = (_Float16)(wa.x - 128); bf[1] = (_Float16)(wa.y - 128);
        bf[2] = (_Float16)(wa.z - 128); bf[3] = (_Float16)(wa.w - 128);
        bf[4] = (_Float16)(wb.x - 128); bf[5] = (_Float16)(wb.y - 128);
        bf[6] = (_Float16)(wb.z - 128); bf[7] = (_Float16)(wb.w - 128);

        acc = __builtin_amdgcn_mfma_f32_16x16x32_f16(af, bf, acc, 0, 0, 0);

        xp += 32;
        wp += 32;
    }

    // Reduce the 8 per-wave partials (each wave covered a disjoint K range).
    __shared__ f32x4 red[NWAVES][64];
    red[wave][lane] = acc;
    __syncthreads();

    if (wave == 0) {
        f32x4 s = red[0][lane];
        #pragma unroll
        for (int w = 1; w < NWAVES; ++w) s += red[w][lane];

        // C/D layout (m89-verified): col = lane&15 (-> o), row = (lane>>4)*4 + r (-> batch)
        const float sc = scale[0];
        const float bo = bias[o];
        const int   brow = kgrp * 4;
        #pragma unroll
        for (int r = 0; r < 4; ++r)
            out[(size_t)(brow + r) * OUT_F + o] = s[r] * sc + bo;
    }
}

extern "C" void kernel_launch(void* const* d_in, const int* in_sizes, int n_in,
                              void* d_out, int out_size, void* d_ws, size_t ws_size,
                              hipStream_t stream) {
    const float* x     = (const float*)d_in[0];
    const int*   wq    = (const int*)d_in[1];
    const float* scale = (const float*)d_in[2];
    const float* bias  = (const float*)d_in[3];
    float*       out   = (float*)d_out;

    dim3 grid(OUT_F / 16);           // 688 o-tiles
    dim3 block(NWAVES * 64);         // 512 threads
    qlinear_mfma<<<grid, block, 0, stream>>>(x, wq, scale, bias, out);
}

// Round 2
// 49.099 us; speedup vs baseline: 1.0011x; 1.0011x over previous
//
#include <hip/hip_runtime.h>
#include <stdint.h>

// CachedCompressedLinear: out[b][o] = sum_k x[b][k] * ((wq[o][k]-128)*scale) + bias[o]
// x: [16][4096] f32, wq: [11008][4096] int32 codes in [0,255], scale: [1] f32,
// bias: [11008] f32, out: [16][11008] f32.
//
// Memory-bound on the 180 MB wq stream (floor ~26-29 us @ ~6.3-7 TB/s).
// R1 was 49 us (3.7 TB/s). R2 changes:
//  - hoist x (A-fragments) into registers once per wave: steady-state global
//    traffic is ONLY the w stream (x loads were stealing L1 miss slots)
//  - explicit 2-deep prefetch pipeline over groups of 4 k-blocks: ~8 load
//    instrs (16 KB) in flight per wave at all times

constexpr int IN_F  = 4096;
constexpr int OUT_F = 11008;
constexpr int NWAVES = 8;                 // waves per block
constexpr int KPW = IN_F / NWAVES;        // 512 k per wave (disjoint slices)
constexpr int NKB = KPW / 32;             // 16 k-blocks of 32 per wave
constexpr int GRP = 4;                    // k-blocks per prefetch group
constexpr int NGRP = NKB / GRP;           // 4 groups

typedef _Float16 f16x8 __attribute__((ext_vector_type(8)));
typedef float    f32x4 __attribute__((ext_vector_type(4)));

__device__ inline f16x8 cvt_codes(int4 a, int4 b) {
    // codes in [0,255]; (c-128) in [-128,127] is EXACT in f16
    f16x8 r;
    r[0] = (_Float16)(short)(a.x - 128);
    r[1] = (_Float16)(short)(a.y - 128);
    r[2] = (_Float16)(short)(a.z - 128);
    r[3] = (_Float16)(short)(a.w - 128);
    r[4] = (_Float16)(short)(b.x - 128);
    r[5] = (_Float16)(short)(b.y - 128);
    r[6] = (_Float16)(short)(b.z - 128);
    r[7] = (_Float16)(short)(b.w - 128);
    return r;
}

__global__ __launch_bounds__(NWAVES * 64, 1)
void qlinear_mfma(const float* __restrict__ x,
                  const int*   __restrict__ wq,
                  const float* __restrict__ scale,
                  const float* __restrict__ bias,
                  float*       __restrict__ out)
{
    const int tid  = threadIdx.x;
    const int lane = tid & 63;
    const int wave = tid >> 6;
    const int obase = blockIdx.x * 16;

    const int ncol = lane & 15;   // B-frag col (o_local); also A-frag row (batch b)
    const int kgrp = lane >> 4;   // 0..3

    const int o  = obase + ncol;
    const int k0 = wave * KPW + kgrp * 8;

    // ---- one-time: hoist this wave's x A-fragments into registers (L2 hits) ----
    const float* xp = x + (size_t)ncol * IN_F + k0;
    f16x8 a[NKB];
    #pragma unroll
    for (int kb = 0; kb < NKB; ++kb) {
        const float4 xa = *reinterpret_cast<const float4*>(xp + kb * 32);
        const float4 xb = *reinterpret_cast<const float4*>(xp + kb * 32 + 4);
        f16x8 t;
        t[0] = (_Float16)xa.x; t[1] = (_Float16)xa.y;
        t[2] = (_Float16)xa.z; t[3] = (_Float16)xa.w;
        t[4] = (_Float16)xb.x; t[5] = (_Float16)xb.y;
        t[6] = (_Float16)xb.z; t[7] = (_Float16)xb.w;
        a[kb] = t;
    }

    // ---- main loop: w is the ONLY global traffic; 2-deep group pipeline ----
    const int* wp = wq + (size_t)o * IN_F + k0;

    int4 cur[2 * GRP], nxt[2 * GRP];
    #pragma unroll
    for (int i = 0; i < GRP; ++i) {
        cur[2 * i]     = *reinterpret_cast<const int4*>(wp + i * 32);
        cur[2 * i + 1] = *reinterpret_cast<const int4*>(wp + i * 32 + 4);
    }

    f32x4 acc = {0.f, 0.f, 0.f, 0.f};

    #pragma unroll
    for (int g = 0; g < NGRP; ++g) {
        if (g < NGRP - 1) {
            #pragma unroll
            for (int i = 0; i < GRP; ++i) {
                nxt[2 * i]     = *reinterpret_cast<const int4*>(wp + ((g + 1) * GRP + i) * 32);
                nxt[2 * i + 1] = *reinterpret_cast<const int4*>(wp + ((g + 1) * GRP + i) * 32 + 4);
            }
        }
        #pragma unroll
        for (int i = 0; i < GRP; ++i) {
            const f16x8 bf = cvt_codes(cur[2 * i], cur[2 * i + 1]);
            acc = __builtin_amdgcn_mfma_f32_16x16x32_f16(a[g * GRP + i], bf, acc, 0, 0, 0);
        }
        if (g < NGRP - 1) {
            #pragma unroll
            for (int i = 0; i < 2 * GRP; ++i) cur[i] = nxt[i];
        }
    }

    // ---- reduce the 8 per-wave partials (disjoint K ranges) ----
    __shared__ f32x4 red[NWAVES][64];
    red[wave][lane] = acc;
    __syncthreads();

    if (wave == 0) {
        f32x4 s = red[0][lane];
        #pragma unroll
        for (int w = 1; w < NWAVES; ++w) s += red[w][lane];

        // C/D layout (m89-verified): col = lane&15 (-> o), row = (lane>>4)*4 + r (-> batch)
        const float sc = scale[0];
        const float bo = bias[o];
        const int   brow = kgrp * 4;
        #pragma unroll
        for (int r = 0; r < 4; ++r)
            out[(size_t)(brow + r) * OUT_F + o] = s[r] * sc + bo;
    }
}

extern "C" void kernel_launch(void* const* d_in, const int* in_sizes, int n_in,
                              void* d_out, int out_size, void* d_ws, size_t ws_size,
                              hipStream_t stream) {
    const float* x     = (const float*)d_in[0];
    const int*   wq    = (const int*)d_in[1];
    const float* scale = (const float*)d_in[2];
    const float* bias  = (const float*)d_in[3];
    float*       out   = (float*)d_out;

    dim3 grid(OUT_F / 16);           // 688 o-tiles
    dim3 block(NWAVES * 64);         // 512 threads
    qlinear_mfma<<<grid, block, 0, stream>>>(x, wq, scale, bias, out);
}